// Round 12
// baseline (360.594 us; speedup 1.0000x reference)
//
#include <hip/hip_runtime.h>

#define B_ 2048
#define T_ 2048
#define SPW 16    // samples per block (MFMA N dimension)
#define GSTR 162  // per-g word stride in exchange buf (16 samples * 10 + 2 pad)
#define QT 512    // timesteps per x staging quarter
#define XSTR 516  // f32 stride per sample row in x LDS (pad: 2-way banks, 16B aligned)

typedef _Float16 f16x8 __attribute__((ext_vector_type(8)));
typedef float    f32x4 __attribute__((ext_vector_type(4)));
typedef unsigned u32x2 __attribute__((ext_vector_type(2)));
typedef unsigned u32x4 __attribute__((ext_vector_type(4)));

__device__ __forceinline__ unsigned pkrtz(float lo, float hi) {
    return __builtin_bit_cast(unsigned, __builtin_amdgcn_cvt_pkrtz(lo, hi));
}

// Round 12 = round 7 (343 us, proven; r11's b128 exchange reverted -- it was
// neutral with 12.6M bank-conflict cycles) + ONE change: the tanh block
// shares one rcp across each value pair, cutting the quarter-rate trans
// issue 8 -> 6 per step (-32 cyc) for +10 full-rate VALU (+20 cyc):
//   e_r = exp2(y'_r); d_r = e_r + 1
//   rp01 = rcp(d0*d1);  1/d0 = d1*rp01;  1/d1 = d0*rp01   (same for 2,3)
//   tanh = (e-1)/(e+1) = (e_r - 1) * (1/d_r)
// Overflow-safe (|y'| <= ~26 so products <= 1e31); precision cost ~2 f32 ulp,
// far below the f16 h-quantization (2.4e-4) that sets absmax. r10's Newton
// failed on its 6-deep dependent chain; this adds only ~8 cyc depth (both
// rcps issue back-to-back after the 4 independent exp2s).
// Everything else byte-for-byte r7: 4-wave tile split, lane-aligned f16
// exchange (sigma-relabeling, HW-verified r3-r11), double-buffered, one
// barrier/step, chained MFMA with ci C-in, x staged in LDS quarters.
__global__ __launch_bounds__(256)
void rnn_mfma_4w7(
    const float* __restrict__ x, const float* __restrict__ W_ih,
    const float* __restrict__ W_hh, const float* __restrict__ b_ih,
    const float* __restrict__ b_hh, const float* __restrict__ W_fc,
    const float* __restrict__ b_fc, float* __restrict__ out)
{
    __shared__ __align__(16) float xl[SPW * XSTR];      // 33 KB x quarter
    __shared__ __align__(16) unsigned ex[2][4 * GSTR];  // [buf][g][s][10 words]
    __shared__ float fcb[4][SPW];

    const int tid = threadIdx.x;
    const int w = tid >> 6;          // wave index == tile index (rows 16w+..)
    const int l = tid & 63;
    const int s = l & 15;            // sample column (C-col / A-M-row / B-N)
    const int g = l >> 4;            // slot group; C row-quad selector
    const int sb = blockIdx.x * SPW;
    const float L2E2 = 2.8853900817779268f;  // 2*log2(e), folded into W/bias

    // ---- A-frags for tile w: slot (g,j) of chunk c holds
    // k = sigma_c(g,j) = 16*(2c+(j>>2)) + 4g + (j&3).   [HW-verified r3-r11]
    f16x8 a0, a1;
#pragma unroll
    for (int j = 0; j < 8; ++j) {
        const int k0 = 16 * (0 + (j >> 2)) + 4 * g + (j & 3);
        const int k1 = 16 * (2 + (j >> 2)) + 4 * g + (j & 3);
        a0[j] = (_Float16)(W_hh[(16 * w + s) * 64 + k0] * L2E2);
        a1[j] = (_Float16)(W_hh[(16 * w + s) * 64 + k1] * L2E2);
    }

    // ---- per-lane C-slot constants: rows 16w + 4g + r
    float wih[4], bw[4];
#pragma unroll
    for (int r = 0; r < 4; ++r) {
        const int row = 16 * w + 4 * g + r;
        wih[r] = W_ih[row] * L2E2;
        bw[r]  = (b_ih[row] + b_hh[row]) * L2E2;
    }

    // ---- exchange addresses (word granularity) ----
    const int exbase = g * GSTR + s * 10;  // this lane's sample slot
    unsigned* const wr0 = &ex[0][exbase + 2 * w];
    unsigned* const wr1 = &ex[1][exbase + 2 * w];
    const unsigned* const rd0 = &ex[0][exbase];
    const unsigned* const rd1 = &ex[1][exbase];

    // ---- state: h[r] = h_state[16w+4g+r] for sample s; h0 = 0.
    float h[4] = {0.0f, 0.0f, 0.0f, 0.0f};

    const float* xg = x + (size_t)sb * T_;  // this block's 16 sample rows
    const float* const xrow = &xl[s * XSTR];

    for (int q = 0; q < 4; ++q) {
        // ---- stage quarter q: 16 rows x 512 f32, coalesced dwordx4 ----
        __syncthreads();  // all waves done reading the previous quarter
        for (int it = tid; it < SPW * (QT / 4); it += 256) {
            const int row = it >> 7;         // 128 float4 chunks per row
            const int c4  = it & 127;
            const float4 v =
                *(const float4*)(xg + (size_t)row * T_ + q * QT + 4 * c4);
            *(float4*)&xl[row * XSTR + 4 * c4] = v;
        }
        __syncthreads();  // quarter visible (drains the staging loads once)

        for (int t0 = 0; t0 < QT; t0 += 4) {
            // group's 4 x values from LDS (lane-private, 2-way banks = free)
            const float4 xq = *(const float4*)(xrow + t0);
            const float xa[4] = {xq.x, xq.y, xq.z, xq.w};

#pragma unroll
            for (int j4 = 0; j4 < 4; ++j4) {
                const int buf = j4 & 1;  // t0 multiple of 4 -> buf = j4&1

                // --- publish this tile's 4 h values (f16-packed, 8B) ---
                const u32x2 pk = {pkrtz(h[0], h[1]), pkrtz(h[2], h[3])};
                *(u32x2*)(buf ? wr1 : wr0) = pk;
                __syncthreads();  // all tiles' h_t visible (vmcnt already 0)

                // --- rebuild full B operands (lane-aligned (g,s) slot) ---
                const unsigned* rp = buf ? rd1 : rd0;
                const u32x2 e0 = *(const u32x2*)(rp + 0);  // tile 0 pair
                const u32x2 e1 = *(const u32x2*)(rp + 2);  // tile 1 pair
                const u32x2 e2 = *(const u32x2*)(rp + 4);  // tile 2 pair
                const u32x2 e3 = *(const u32x2*)(rp + 6);  // tile 3 pair
                const u32x4 q0 = {e0.x, e0.y, e1.x, e1.y};
                const u32x4 q1 = {e2.x, e2.y, e3.x, e3.y};
                const f16x8 b0 = __builtin_bit_cast(f16x8, q0);  // k =  0..31
                const f16x8 b1 = __builtin_bit_cast(f16x8, q1);  // k = 32..63

                // --- acc init (bias + x*w_ih as C-in) + 2 chained MFMA ---
                f32x4 ci;
#pragma unroll
                for (int r = 0; r < 4; ++r) ci[r] = fmaf(xa[j4], wih[r], bw[r]);
                const f32x4 p0 =
                    __builtin_amdgcn_mfma_f32_16x16x32_f16(a0, b0, ci, 0, 0, 0);
                const f32x4 acc =
                    __builtin_amdgcn_mfma_f32_16x16x32_f16(a1, b1, p0, 0, 0, 0);

                // --- tanh = (e-1)/(e+1), shared-rcp pairs: 6 trans total ---
                float ev[4], dv[4];
#pragma unroll
                for (int r = 0; r < 4; ++r) {
                    ev[r] = __builtin_amdgcn_exp2f(acc[r]);
                    dv[r] = ev[r] + 1.0f;
                }
                const float rp01 = __builtin_amdgcn_rcpf(dv[0] * dv[1]);
                const float rp23 = __builtin_amdgcn_rcpf(dv[2] * dv[3]);
                h[0] = (ev[0] - 1.0f) * (dv[1] * rp01);
                h[1] = (ev[1] - 1.0f) * (dv[0] * rp01);
                h[2] = (ev[2] - 1.0f) * (dv[3] * rp23);
                h[3] = (ev[3] - 1.0f) * (dv[2] * rp23);
            }
        }
    }

    // ---- FC head: out[s] = sum_row h[row][s] * W_fc[row] + b_fc ----
    float p = 0.0f;
#pragma unroll
    for (int r = 0; r < 4; ++r) p = fmaf(h[r], W_fc[16 * w + 4 * g + r], p);
    p += __shfl_down(p, 32);
    p += __shfl_down(p, 16);
    if (l < 16) fcb[w][l] = p;
    __syncthreads();
    if (tid < 16)
        out[sb + tid] = (fcb[0][tid] + fcb[1][tid]) + (fcb[2][tid] + fcb[3][tid]) + b_fc[0];
}

extern "C" void kernel_launch(void* const* d_in, const int* in_sizes, int n_in,
                              void* d_out, int out_size, void* d_ws, size_t ws_size,
                              hipStream_t stream) {
    const float* x    = (const float*)d_in[0];
    const float* W_ih = (const float*)d_in[1];
    const float* W_hh = (const float*)d_in[2];
    const float* b_ih = (const float*)d_in[3];
    const float* b_hh = (const float*)d_in[4];
    const float* W_fc = (const float*)d_in[5];
    const float* b_fc = (const float*)d_in[6];
    float* out = (float*)d_out;

    rnn_mfma_4w7<<<dim3(B_ / SPW), dim3(256), 0, stream>>>(x, W_ih, W_hh, b_ih, b_hh,
                                                           W_fc, b_fc, out);
}

// Round 13
// 344.010 us; speedup vs baseline: 1.0482x; 1.0482x over previous
//
#include <hip/hip_runtime.h>

#define B_ 2048
#define T_ 2048
#define SPW 16    // samples per block (MFMA N dimension)
#define GSTR 162  // per-g word stride in exchange buf (16 samples * 10 + 2 pad)
#define QT 512    // timesteps per x staging quarter
#define XSTR 516  // f32 stride per sample row in x LDS (pad: 2-way banks, 16B aligned)

typedef _Float16 f16x8 __attribute__((ext_vector_type(8)));
typedef float    f32x4 __attribute__((ext_vector_type(4)));
typedef unsigned u32x2 __attribute__((ext_vector_type(2)));
typedef unsigned u32x4 __attribute__((ext_vector_type(4)));

__device__ __forceinline__ unsigned pkrtz(float lo, float hi) {
    return __builtin_bit_cast(unsigned, __builtin_amdgcn_cvt_pkrtz(lo, hi));
}

// FINAL (= round 7, the measured best at 343 us). 4-wave cooperative MFMA
// RNN; structural floor of this problem on gfx950 per r8-r12 bracketing:
// per-step serial ring ~402 cyc = tanh(8 trans @ quarter-rate, ~150) ->
// pk/ds_write/barrier(~55) -> ds_read wait(~130) -> 2 chained MFMA(~70).
//  - wave w owns M-tile w (rows 16w..16w+15) of the 64x64 W_hh; 16 samples
//    are the MFMA N dimension.
//  - sigma-relabeling (HW-verified r3-r12): slot (g,j) of K-chunk c <-> k =
//    16*(2c+(j>>2)) + 4g + (j&3), so the exchange is LANE-ALIGNED: consumer
//    lane (s,g) chunk c reads producer lane (s,g) of waves 2c,2c+1.
//    1 ds_write_b64 + 4 ds_read_b64 per step, double-buffered, ONE
//    __syncthreads per step, zero bank conflicts (stride-10 slots).
//  - x is staged through LDS in f32 quarters so the recurrence loop has ZERO
//    global memory and the barrier's implicit vmcnt(0) drain is a no-op
//    (r5/r6 evidence: an in-loop global x prefetch serializes ~200+ cyc/step
//    into the ring via that drain).
//  - bias + x*w_ih enter as the MFMA C-operand; tanh via exp2 with 2*log2(e)
//    folded into all weights/biases at init.
__global__ __launch_bounds__(256)
void rnn_mfma_4w3(
    const float* __restrict__ x, const float* __restrict__ W_ih,
    const float* __restrict__ W_hh, const float* __restrict__ b_ih,
    const float* __restrict__ b_hh, const float* __restrict__ W_fc,
    const float* __restrict__ b_fc, float* __restrict__ out)
{
    __shared__ __align__(16) float xl[SPW * XSTR];      // 33 KB x quarter
    __shared__ __align__(16) unsigned ex[2][4 * GSTR];  // [buf][g][s][10 words]
    __shared__ float fcb[4][SPW];

    const int tid = threadIdx.x;
    const int w = tid >> 6;          // wave index == tile index (rows 16w+..)
    const int l = tid & 63;
    const int s = l & 15;            // sample column (C-col / A-M-row / B-N)
    const int g = l >> 4;            // slot group; C row-quad selector
    const int sb = blockIdx.x * SPW;
    const float L2E2 = 2.8853900817779268f;  // 2*log2(e), folded into W/bias

    // ---- A-frags for tile w: slot (g,j) of chunk c holds
    // k = sigma_c(g,j) = 16*(2c+(j>>2)) + 4g + (j&3).
    f16x8 a0, a1;
#pragma unroll
    for (int j = 0; j < 8; ++j) {
        const int k0 = 16 * (0 + (j >> 2)) + 4 * g + (j & 3);
        const int k1 = 16 * (2 + (j >> 2)) + 4 * g + (j & 3);
        a0[j] = (_Float16)(W_hh[(16 * w + s) * 64 + k0] * L2E2);
        a1[j] = (_Float16)(W_hh[(16 * w + s) * 64 + k1] * L2E2);
    }

    // ---- per-lane C-slot constants: rows 16w + 4g + r
    float wih[4], bw[4];
#pragma unroll
    for (int r = 0; r < 4; ++r) {
        const int row = 16 * w + 4 * g + r;
        wih[r] = W_ih[row] * L2E2;
        bw[r]  = (b_ih[row] + b_hh[row]) * L2E2;
    }

    // ---- exchange addresses (word granularity) ----
    const int exbase = g * GSTR + s * 10;  // this lane's sample slot
    unsigned* const wr0 = &ex[0][exbase + 2 * w];
    unsigned* const wr1 = &ex[1][exbase + 2 * w];
    const unsigned* const rd0 = &ex[0][exbase];
    const unsigned* const rd1 = &ex[1][exbase];

    // ---- state: h[r] = h_state[16w+4g+r] for sample s; h0 = 0.
    float h[4] = {0.0f, 0.0f, 0.0f, 0.0f};

    const float* xg = x + (size_t)sb * T_;  // this block's 16 sample rows
    const float* const xrow = &xl[s * XSTR];

    for (int q = 0; q < 4; ++q) {
        // ---- stage quarter q: 16 rows x 512 f32, coalesced dwordx4 ----
        __syncthreads();  // all waves done reading the previous quarter
        for (int it = tid; it < SPW * (QT / 4); it += 256) {
            const int row = it >> 7;         // 128 float4 chunks per row
            const int c4  = it & 127;
            const float4 v =
                *(const float4*)(xg + (size_t)row * T_ + q * QT + 4 * c4);
            *(float4*)&xl[row * XSTR + 4 * c4] = v;
        }
        __syncthreads();  // quarter visible (drains the staging loads once)

        for (int t0 = 0; t0 < QT; t0 += 4) {
            // group's 4 x values from LDS (lane-private, 2-way banks = free)
            const float4 xq = *(const float4*)(xrow + t0);
            const float xa[4] = {xq.x, xq.y, xq.z, xq.w};

#pragma unroll
            for (int j4 = 0; j4 < 4; ++j4) {
                const int buf = j4 & 1;  // t0 multiple of 4 -> buf = j4&1

                // --- publish this tile's 4 h values (f16-packed, 8B) ---
                const u32x2 pk = {pkrtz(h[0], h[1]), pkrtz(h[2], h[3])};
                *(u32x2*)(buf ? wr1 : wr0) = pk;
                __syncthreads();  // all tiles' h_t visible (vmcnt already 0)

                // --- rebuild full B operands (lane-aligned (g,s) slot) ---
                const unsigned* rp = buf ? rd1 : rd0;
                const u32x2 e0 = *(const u32x2*)(rp + 0);  // tile 0 pair
                const u32x2 e1 = *(const u32x2*)(rp + 2);  // tile 1 pair
                const u32x2 e2 = *(const u32x2*)(rp + 4);  // tile 2 pair
                const u32x2 e3 = *(const u32x2*)(rp + 6);  // tile 3 pair
                const u32x4 q0 = {e0.x, e0.y, e1.x, e1.y};
                const u32x4 q1 = {e2.x, e2.y, e3.x, e3.y};
                const f16x8 b0 = __builtin_bit_cast(f16x8, q0);  // k =  0..31
                const f16x8 b1 = __builtin_bit_cast(f16x8, q1);  // k = 32..63

                // --- acc init (bias + x*w_ih as C-in) + 2 chained MFMA ---
                f32x4 ci;
#pragma unroll
                for (int r = 0; r < 4; ++r) ci[r] = fmaf(xa[j4], wih[r], bw[r]);
                const f32x4 p0 =
                    __builtin_amdgcn_mfma_f32_16x16x32_f16(a0, b0, ci, 0, 0, 0);
                const f32x4 acc =
                    __builtin_amdgcn_mfma_f32_16x16x32_f16(a1, b1, p0, 0, 0, 0);

                // --- tanh(pre) = 1 - 2/(exp2(2log2e*pre)+1): 8 trans ---
#pragma unroll
                for (int r = 0; r < 4; ++r) {
                    const float e = __builtin_amdgcn_exp2f(acc[r]);
                    h[r] = fmaf(-2.0f, __builtin_amdgcn_rcpf(e + 1.0f), 1.0f);
                }
            }
        }
    }

    // ---- FC head: out[s] = sum_row h[row][s] * W_fc[row] + b_fc ----
    float p = 0.0f;
#pragma unroll
    for (int r = 0; r < 4; ++r) p = fmaf(h[r], W_fc[16 * w + 4 * g + r], p);
    p += __shfl_down(p, 32);
    p += __shfl_down(p, 16);
    if (l < 16) fcb[w][l] = p;
    __syncthreads();
    if (tid < 16)
        out[sb + tid] = (fcb[0][tid] + fcb[1][tid]) + (fcb[2][tid] + fcb[3][tid]) + b_fc[0];
}

extern "C" void kernel_launch(void* const* d_in, const int* in_sizes, int n_in,
                              void* d_out, int out_size, void* d_ws, size_t ws_size,
                              hipStream_t stream) {
    const float* x    = (const float*)d_in[0];
    const float* W_ih = (const float*)d_in[1];
    const float* W_hh = (const float*)d_in[2];
    const float* b_ih = (const float*)d_in[3];
    const float* b_hh = (const float*)d_in[4];
    const float* W_fc = (const float*)d_in[5];
    const float* b_fc = (const float*)d_in[6];
    float* out = (float*)d_out;

    rnn_mfma_4w3<<<dim3(B_ / SPW), dim3(256), 0, stream>>>(x, W_ih, W_hh, b_ih, b_hh,
                                                           W_fc, b_fc, out);
}

// Round 14
// 341.667 us; speedup vs baseline: 1.0554x; 1.0069x over previous
//
#include <hip/hip_runtime.h>

#define B_ 2048
#define T_ 2048
#define SPW 16    // samples per block (MFMA N dimension)
#define GSTR 162  // per-g word stride in exchange buf (16 samples * 10 + 2 pad)
#define QT 512    // timesteps per x staging quarter
#define XSTR 516  // f32 stride per sample row in x LDS (pad: 2-way banks, 16B aligned)

typedef _Float16 f16x8 __attribute__((ext_vector_type(8)));
typedef float    f32x4 __attribute__((ext_vector_type(4)));
typedef unsigned u32x2 __attribute__((ext_vector_type(2)));
typedef unsigned u32x4 __attribute__((ext_vector_type(4)));

__device__ __forceinline__ unsigned pkrtz(float lo, float hi) {
    return __builtin_bit_cast(unsigned, __builtin_amdgcn_cvt_pkrtz(lo, hi));
}

// Round 14 = round 7 (344 us, proven) + ONE change: the h-independent
// ci = bias + x*w_ih affine moves from post-barrier to the ds_write->barrier
// window. That window is currently empty, so the barrier's lgkmcnt(0) eats
// the full ds_write latency; the 4 FMAs both fill it and leave the
// post-barrier chain (read -> MFMA) 4 dependent FMAs shorter. This isolates
// the good half of r11 (whose stride-12 exchange added 12.6M bank-conflict
// cycles that masked it); r6's failure of the same hoist was the global-x
// vmcnt interaction, absent since r7 staged x in LDS.
// Everything else byte-for-byte r7: 4-wave tile split, stride-10 lane-aligned
// f16 exchange (sigma-relabeling, HW-verified r3-r13), double-buffered, one
// __syncthreads/step, chained MFMA with ci C-in, exp2+rcp tanh, x staged in
// LDS quarters (zero global memory in the recurrence loop).
__global__ __launch_bounds__(256)
void rnn_mfma_4w8(
    const float* __restrict__ x, const float* __restrict__ W_ih,
    const float* __restrict__ W_hh, const float* __restrict__ b_ih,
    const float* __restrict__ b_hh, const float* __restrict__ W_fc,
    const float* __restrict__ b_fc, float* __restrict__ out)
{
    __shared__ __align__(16) float xl[SPW * XSTR];      // 33 KB x quarter
    __shared__ __align__(16) unsigned ex[2][4 * GSTR];  // [buf][g][s][10 words]
    __shared__ float fcb[4][SPW];

    const int tid = threadIdx.x;
    const int w = tid >> 6;          // wave index == tile index (rows 16w+..)
    const int l = tid & 63;
    const int s = l & 15;            // sample column (C-col / A-M-row / B-N)
    const int g = l >> 4;            // slot group; C row-quad selector
    const int sb = blockIdx.x * SPW;
    const float L2E2 = 2.8853900817779268f;  // 2*log2(e), folded into W/bias

    // ---- A-frags for tile w: slot (g,j) of chunk c holds
    // k = sigma_c(g,j) = 16*(2c+(j>>2)) + 4g + (j&3).   [HW-verified r3-r13]
    f16x8 a0, a1;
#pragma unroll
    for (int j = 0; j < 8; ++j) {
        const int k0 = 16 * (0 + (j >> 2)) + 4 * g + (j & 3);
        const int k1 = 16 * (2 + (j >> 2)) + 4 * g + (j & 3);
        a0[j] = (_Float16)(W_hh[(16 * w + s) * 64 + k0] * L2E2);
        a1[j] = (_Float16)(W_hh[(16 * w + s) * 64 + k1] * L2E2);
    }

    // ---- per-lane C-slot constants: rows 16w + 4g + r
    float wih[4], bw[4];
#pragma unroll
    for (int r = 0; r < 4; ++r) {
        const int row = 16 * w + 4 * g + r;
        wih[r] = W_ih[row] * L2E2;
        bw[r]  = (b_ih[row] + b_hh[row]) * L2E2;
    }

    // ---- exchange addresses (word granularity) ----
    const int exbase = g * GSTR + s * 10;  // this lane's sample slot
    unsigned* const wr0 = &ex[0][exbase + 2 * w];
    unsigned* const wr1 = &ex[1][exbase + 2 * w];
    const unsigned* const rd0 = &ex[0][exbase];
    const unsigned* const rd1 = &ex[1][exbase];

    // ---- state: h[r] = h_state[16w+4g+r] for sample s; h0 = 0.
    float h[4] = {0.0f, 0.0f, 0.0f, 0.0f};

    const float* xg = x + (size_t)sb * T_;  // this block's 16 sample rows
    const float* const xrow = &xl[s * XSTR];

    for (int q = 0; q < 4; ++q) {
        // ---- stage quarter q: 16 rows x 512 f32, coalesced dwordx4 ----
        __syncthreads();  // all waves done reading the previous quarter
        for (int it = tid; it < SPW * (QT / 4); it += 256) {
            const int row = it >> 7;         // 128 float4 chunks per row
            const int c4  = it & 127;
            const float4 v =
                *(const float4*)(xg + (size_t)row * T_ + q * QT + 4 * c4);
            *(float4*)&xl[row * XSTR + 4 * c4] = v;
        }
        __syncthreads();  // quarter visible (drains the staging loads once)

        for (int t0 = 0; t0 < QT; t0 += 4) {
            // group's 4 x values from LDS (lane-private, 2-way banks = free)
            const float4 xq = *(const float4*)(xrow + t0);
            const float xa[4] = {xq.x, xq.y, xq.z, xq.w};

#pragma unroll
            for (int j4 = 0; j4 < 4; ++j4) {
                const int buf = j4 & 1;  // t0 multiple of 4 -> buf = j4&1

                // --- publish this tile's 4 h values (f16-packed, 8B) ---
                const u32x2 pk = {pkrtz(h[0], h[1]), pkrtz(h[2], h[3])};
                *(u32x2*)(buf ? wr1 : wr0) = pk;

                // --- h-independent affine fills the write->barrier window ---
                f32x4 ci;
#pragma unroll
                for (int r = 0; r < 4; ++r) ci[r] = fmaf(xa[j4], wih[r], bw[r]);

                __syncthreads();  // all tiles' h_t visible (vmcnt already 0)

                // --- rebuild full B operands (lane-aligned (g,s) slot) ---
                const unsigned* rp = buf ? rd1 : rd0;
                const u32x2 e0 = *(const u32x2*)(rp + 0);  // tile 0 pair
                const u32x2 e1 = *(const u32x2*)(rp + 2);  // tile 1 pair
                const u32x2 e2 = *(const u32x2*)(rp + 4);  // tile 2 pair
                const u32x2 e3 = *(const u32x2*)(rp + 6);  // tile 3 pair
                const u32x4 q0 = {e0.x, e0.y, e1.x, e1.y};
                const u32x4 q1 = {e2.x, e2.y, e3.x, e3.y};
                const f16x8 b0 = __builtin_bit_cast(f16x8, q0);  // k =  0..31
                const f16x8 b1 = __builtin_bit_cast(f16x8, q1);  // k = 32..63

                // --- 2 chained MFMA (C-in carries bias + x*w_ih) ---
                const f32x4 p0 =
                    __builtin_amdgcn_mfma_f32_16x16x32_f16(a0, b0, ci, 0, 0, 0);
                const f32x4 acc =
                    __builtin_amdgcn_mfma_f32_16x16x32_f16(a1, b1, p0, 0, 0, 0);

                // --- tanh(pre) = 1 - 2/(exp2(2log2e*pre)+1): 8 trans ---
#pragma unroll
                for (int r = 0; r < 4; ++r) {
                    const float e = __builtin_amdgcn_exp2f(acc[r]);
                    h[r] = fmaf(-2.0f, __builtin_amdgcn_rcpf(e + 1.0f), 1.0f);
                }
            }
        }
    }

    // ---- FC head: out[s] = sum_row h[row][s] * W_fc[row] + b_fc ----
    float p = 0.0f;
#pragma unroll
    for (int r = 0; r < 4; ++r) p = fmaf(h[r], W_fc[16 * w + 4 * g + r], p);
    p += __shfl_down(p, 32);
    p += __shfl_down(p, 16);
    if (l < 16) fcb[w][l] = p;
    __syncthreads();
    if (tid < 16)
        out[sb + tid] = (fcb[0][tid] + fcb[1][tid]) + (fcb[2][tid] + fcb[3][tid]) + b_fc[0];
}

extern "C" void kernel_launch(void* const* d_in, const int* in_sizes, int n_in,
                              void* d_out, int out_size, void* d_ws, size_t ws_size,
                              hipStream_t stream) {
    const float* x    = (const float*)d_in[0];
    const float* W_ih = (const float*)d_in[1];
    const float* W_hh = (const float*)d_in[2];
    const float* b_ih = (const float*)d_in[3];
    const float* b_hh = (const float*)d_in[4];
    const float* W_fc = (const float*)d_in[5];
    const float* b_fc = (const float*)d_in[6];
    float* out = (float*)d_out;

    rnn_mfma_4w8<<<dim3(B_ / SPW), dim3(256), 0, stream>>>(x, W_ih, W_hh, b_ih, b_hh,
                                                           W_fc, b_fc, out);
}